// Round 14
// baseline (272.787 us; speedup 1.0000x reference)
//
#include <hip/hip_runtime.h>
#include <hip/hip_bf16.h>

#define NXC 440
#define NYC 500
#define GCELLS (NXC * NYC)            // 220000 (NZ = 1)
#define NWORDS ((GCELLS + 31) / 32)   // 6875 bitmap words
#define MAXV 40000
#define MAXP 32
#define SCANB ((NWORDS + 255) / 256)  // 27 blocks for k_scan
#define TPAD 16                       // ticket stride (ints): 1 counter / 64B line
#define CG 1024                       // k_cell grid (no LDS cap anymore)

// Expected outputs are bf16-quantized but stored as fp32: round-trip.
__device__ __forceinline__ float bf16r(float x) {
    return __bfloat162float(__float2bfloat16(x));
}

// Linear cell index exactly as the numpy reference (fp32 ops). Invalid -> -1.
__device__ __forceinline__ int point_cell(const float* p) {
    float x = p[0], y = p[1], z = p[2];
    bool valid = (x >= 0.0f) && (x < 70.4f) &&
                 (y >= -40.0f) && (y < 40.0f) &&
                 (z >= -3.0f) && (z < 1.0f);
    if (!valid) return -1;
    int cx = (int)floorf(x / 0.16f);
    int cy = (int)floorf((y + 40.0f) / 0.16f);
    // z in [-3,1) -> cz == 0 always (NZ = 1)
    cx = min(max(cx, 0), NXC - 1);
    cy = min(max(cy, 0), NYC - 1);
    return cy * NXC + cx;
}

// Pass 1: cellid cache + DIRECT global occupancy bitmap.
// Monotonic-OR trick: plain load can never read a spurious 1, so read-first
// then atomicOr-on-miss is safe even with stale per-XCD L2 (stale 0 just
// causes a redundant atomicOr). Cuts 2M atomics to ~350k (~25 G-atomic/s).
// Also zero-inits ticket for k_scatter (occ zeroed by memset before launch).
__global__ __launch_bounds__(256) void k_cell(const float* pts, int* cellid,
                                              unsigned* occ, int* ticket, int n) {
    int tid = blockIdx.x * 256 + threadIdx.x;
    const int stride = CG * 256;
    for (int i = tid; i < n; i += stride) {
        int cell = point_cell(pts + (size_t)i * 5);
        if (cellid) cellid[i] = cell;
        if (cell >= 0) {
            int w = cell >> 5;
            unsigned mk = 1u << (cell & 31);
            if (!(occ[w] & mk)) atomicOr(&occ[w], mk);
        }
    }
    for (int idx = tid; idx < MAXV * TPAD; idx += stride) ticket[idx] = 0;
}

// Word-level exclusive scan (self-computed cross-block base: occ is 27.5 KB,
// L2-resident) -> wordprefix; emit coords for kept voxels.
__global__ __launch_bounds__(256) void k_scan(const unsigned* occ,
                                              int* wpre, float* out_coords) {
    int b = blockIdx.x, t = threadIdx.x;
    // cross-block base: popcount of all words before this block's slice
    __shared__ int sb[256];
    int pre = 0;
    for (int w = t; w < b * 256; w += 256) pre += __popc(occ[w]);
    sb[t] = pre;
    __syncthreads();
    for (int d = 128; d > 0; d >>= 1) {
        if (t < d) sb[t] += sb[t + d];
        __syncthreads();
    }
    int base = sb[0];
    // intra-block scan over this slice
    int w = b * 256 + t;
    unsigned o = (w < NWORDS) ? occ[w] : 0u;
    int c = __popc(o);
    __shared__ int s[256];
    s[t] = c;
    __syncthreads();
    for (int d = 1; d < 256; d <<= 1) {
        int v = (t >= d) ? s[t - d] : 0;
        __syncthreads();
        s[t] += v;
        __syncthreads();
    }
    int vid = base + (s[t] - c);
    if (w < NWORDS) {
        wpre[w] = vid;
        if (vid < MAXV) {
            unsigned m = o;
            while (m) {
                int bit = __ffs(m) - 1;
                m &= m - 1u;
                if (vid < MAXV) {
                    int cell = w * 32 + bit;
                    int cy = cell / NXC, cx = cell - cy * NXC;
                    float* oc = out_coords + (size_t)vid * 3;
                    oc[0] = 0.0f;
                    oc[1] = bf16r((float)cy);
                    oc[2] = bf16r((float)cx);
                }
                ++vid;
            }
        }
    }
}

__device__ __forceinline__ void scat1(int cell, int i, const unsigned* occ,
                                      const int* wpre, int* ticket, int* seg, int S) {
    if (cell < 0) return;
    int w = cell >> 5, b = cell & 31;
    int vid = wpre[w] + __popc(occ[w] & ((1u << b) - 1u));
    if (vid >= MAXV) return;
    int t = atomicAdd(&ticket[(size_t)vid * TPAD], 1);
    if (t < S) seg[(size_t)vid * S + t] = i;
}

// Scatter point indices into fixed-stride per-voxel segments, 8 pts/thread
// via 2x int4 cellid loads.
__global__ __launch_bounds__(256) void k_scatter(const float* pts, const int* cellid,
                                                 const unsigned* occ, const int* wpre,
                                                 int* ticket, int* seg, int S, int n) {
    int g = blockIdx.x * 256 + threadIdx.x;
    int n8 = n >> 3;
    if (cellid) {
        if (g < n8) {
            const int4* c4 = (const int4*)cellid;
            int4 ca = c4[g * 2], cb = c4[g * 2 + 1];
            int i0 = g * 8;
            scat1(ca.x, i0 + 0, occ, wpre, ticket, seg, S);
            scat1(ca.y, i0 + 1, occ, wpre, ticket, seg, S);
            scat1(ca.z, i0 + 2, occ, wpre, ticket, seg, S);
            scat1(ca.w, i0 + 3, occ, wpre, ticket, seg, S);
            scat1(cb.x, i0 + 4, occ, wpre, ticket, seg, S);
            scat1(cb.y, i0 + 5, occ, wpre, ticket, seg, S);
            scat1(cb.z, i0 + 6, occ, wpre, ticket, seg, S);
            scat1(cb.w, i0 + 7, occ, wpre, ticket, seg, S);
        }
        if (g == 0) {
            for (int i = n8 * 8; i < n; ++i)
                scat1(cellid[i], i, occ, wpre, ticket, seg, S);
        }
    } else {
        if (g < n) scat1(point_cell(pts + (size_t)g * 5), g, occ, wpre, ticket, seg, S);
    }
}

// One wave per voxel: rank by original index (stable), gather feats, write ALL
// 32 slots (zeros for empty ranks) + num_points. No output memset needed.
__global__ __launch_bounds__(256) void k_fill(const float* pts, const int* ticket,
                                              const int* seg, int S,
                                              float* out_vox, float* out_np) {
    __shared__ int slot[4][MAXP];
    int wave = threadIdx.x >> 6, lane = threadIdx.x & 63;
    int v = blockIdx.x * 4 + wave;     // MAXV % 4 == 0 -> always in range
    int ntot = ticket[(size_t)v * TPAD];
    int nn = min(ntot, S);             // S >= 32; P(cell count > S) ~ 0
    int m = min(nn, MAXP);
    int myidx = (lane < nn) ? seg[(size_t)v * S + lane] : 0x7fffffff;
    int rank = 0;
    for (int j = 0; j < nn; ++j) {
        int ej = __shfl(myidx, j, 64);
        rank += (ej < myidx) ? 1 : 0;
    }
    if (lane < nn && rank < MAXP) slot[wave][rank] = myidx;
    __syncthreads();   // order LDS scatter before readback (all threads reach)
    if (lane < MAXP) {
        float* dst = out_vox + ((size_t)v * MAXP + lane) * 5;
        if (lane < m) {
            const float* src = pts + (size_t)slot[wave][lane] * 5;
            #pragma unroll
            for (int k = 0; k < 5; ++k) dst[k] = bf16r(src[k]);
        } else {
            #pragma unroll
            for (int k = 0; k < 5; ++k) dst[k] = 0.0f;
        }
    }
    if (lane == 0) out_np[v] = bf16r((float)m);
}

extern "C" void kernel_launch(void* const* d_in, const int* in_sizes, int n_in,
                              void* d_out, int out_size, void* d_ws, size_t ws_size,
                              hipStream_t stream) {
    const float* pts = (const float*)d_in[0];
    int n = in_sizes[0] / 5;

    float* out = (float*)d_out;   // fp32 storage, bf16-precision values
    float* out_vox    = out;                                   // MAXV*32*5
    float* out_coords = out + (size_t)MAXV * MAXP * 5;         // MAXV*3
    float* out_np     = out_coords + (size_t)MAXV * 3;         // MAXV

    // ws ints: cellid[n]? + occ[NWORDS] + ticket[MAXV*TPAD] + wpre[NWORDS]
    //          + seg[MAXV*S]   (~21 MB at S=64 with cellid)
    const size_t fixed_ints = 2 * (size_t)NWORDS + (size_t)MAXV * TPAD;
    int S = 32; bool use_cid = false;
    {
        auto fits = [&](int s, bool cid) {
            size_t ints = fixed_ints + (size_t)MAXV * s + (cid ? (size_t)n : 0);
            return ints * sizeof(int) <= ws_size;
        };
        if      (fits(64, true))  { S = 64; use_cid = true;  }
        else if (fits(48, true))  { S = 48; use_cid = true;  }
        else if (fits(40, false)) { S = 40; use_cid = false; }
        else                      { S = 32; use_cid = false; }
    }

    int* ws = (int*)d_ws;
    int* cellid   = use_cid ? ws : nullptr;                    // n (optional)
    unsigned* occ = (unsigned*)(ws + (use_cid ? (size_t)n : 0)); // NWORDS (memset)
    int* ticket   = (int*)(occ + NWORDS);                      // MAXV*TPAD (zeroed in k_cell)
    int* wpre     = ticket + (size_t)MAXV * TPAD;              // NWORDS
    int* seg      = wpre + NWORDS;                             // MAXV * S

    // occ must be zero BEFORE k_cell's read-first atomics (27.5 KB, ~2 us).
    hipMemsetAsync(occ, 0, (size_t)NWORDS * sizeof(unsigned), stream);

    int nb  = (n + 255) / 256;
    int nb8 = (n / 8 + 255) / 256;
    k_cell<<<CG, 256, 0, stream>>>(pts, cellid, occ, ticket, n);
    k_scan<<<SCANB, 256, 0, stream>>>(occ, wpre, out_coords);
    k_scatter<<<(use_cid ? nb8 : nb), 256, 0, stream>>>(pts, cellid, occ, wpre,
                                                        ticket, seg, S, n);
    k_fill<<<(MAXV + 3) / 4, 256, 0, stream>>>(pts, ticket, seg, S, out_vox, out_np);
}